// Round 15
// baseline (101.959 us; speedup 1.0000x reference)
//
#include <hip/hip_runtime.h>
#include <hip/hip_bf16.h>

// Problem constants (SelectSphereConv, graph level 6)
#define VN 40962
#define NGB 5121          // blocks of 8 vertices (two pipelined sub-groups of 4)
#define LDA_B 1168        // A-tile row stride bytes (576*2 + 16 pad)
#define LDS_TOT 18688     // 16 rows x 1168 -- single A-tile (both subs reuse it)
#define XT_BYTES (VN * 512)

typedef float f32x4 __attribute__((ext_vector_type(4)));
typedef __bf16 bf16x8 __attribute__((ext_vector_type(8)));

// ---------------------------------------------------------------------------
// Kernel 1: transpose x [256(t=b*64+c), V] f32 -> x_t [V, 256] bf16
// ---------------------------------------------------------------------------
__global__ __launch_bounds__(256) void k_transpose(const float* __restrict__ x,
                                                   __bf16* __restrict__ xt) {
    __shared__ __bf16 tile[64][65];
    const int v0 = blockIdx.x * 64;
    const int t0 = blockIdx.y * 64;
    const int lane = threadIdx.x & 63;
    const int sub = threadIdx.x >> 6;

#pragma unroll
    for (int r = 0; r < 16; ++r) {
        const int t = t0 + r * 4 + sub;
        const int v = v0 + lane;
        float val = (v < VN) ? x[(size_t)t * VN + v] : 0.f;   // coalesced
        tile[r * 4 + sub][lane] = (__bf16)val;
    }
    __syncthreads();
#pragma unroll
    for (int r = 0; r < 16; ++r) {
        const int vv = r * 4 + sub;
        const int v = v0 + vv;
        if (v < VN) xt[(size_t)v * 256 + t0 + lane] = tile[lane][vv];  // coalesced
    }
}

// ---------------------------------------------------------------------------
// Kernel 2: pre-swizzle conv_w into MFMA fragment order (R1/R3-validated):
//   wf[((w*18+ks)*64 + lane)*8 + e] = conv_w[(w*16+(lane&15))*576
//                                            + ks*32 + (lane>>4)*8 + e]
// ---------------------------------------------------------------------------
__global__ __launch_bounds__(64) void k_wprep(const float* __restrict__ conv_w,
                                              __bf16* __restrict__ wf) {
    const int id = blockIdx.x;           // w*18 + ks, 0..71
    const int ks = id % 18;
    const int w  = id / 18;
    const int lane = threadIdx.x;        // 0..63
    const int o  = w * 16 + (lane & 15);
    const int kb = (lane >> 4) * 8;
    const float* wrow = conv_w + (size_t)o * 576 + ks * 32 + kb;
    bf16x8 f;
#pragma unroll
    for (int e = 0; e < 8; ++e) f[e] = (__bf16)wrow[e];
    *(bf16x8*)(wf + ((size_t)id * 64 + lane) * 8) = f;
}

// ---------------------------------------------------------------------------
// Kernel 3: fused gather + interpolate + conv. 8 vertices/block as TWO
//   pipelined sub-groups of 4. Raw barriers (lgkmcnt(0)-only + s_barrier,
//   R3/R5-validated) keep sub1's 36 gathers IN FLIGHT across sub0's
//   MFMA+store -- unlike __syncthreads' forced vmcnt(0) drain. Single
//   A-tile (18688 B -> 8-block/CU LDS cap). Direct store (R13-validated
//   swapped-operand mapping) + bijective XCD swizzle (R14: write RMW fix,
//   WRITE 103->42 MB ideal). NO waves-per-EU hint (R8/R9: spills).
// ---------------------------------------------------------------------------
__global__ __launch_bounds__(256) void k_fused(const __bf16* __restrict__ xt,
                                               const int* __restrict__ index,
                                               const float* __restrict__ itp_mat,
                                               const __bf16* __restrict__ wf,
                                               const float* __restrict__ conv_b,
                                               float* __restrict__ out) {
    __shared__ char smem[LDS_TOT];

    const int tid  = threadIdx.x;
    const int lane = tid & 63;
    const int w    = tid >> 6;      // batch b in phase 1; o-tile in MFMA
    const int l16  = lane & 15;
    const int g4   = lane >> 4;

    // ---- bijective XCD swizzle: NGB = 5121 = 8*640 + 1 ----
    // xcd = bid & 7 (HW round-robin): XCD 0 owns [0,641), XCD k>=1 owns
    // [641+(k-1)*640, +640). Bijective on 0..5120; contiguous v per XCD.
    int g;
    {
        const int bid = blockIdx.x;
        const int xcd = bid & 7;
        const int idx = bid >> 3;
        g = (xcd == 0) ? idx : (641 + (xcd - 1) * 640 + idx);
    }
    const int v0 = g * 8;

    // store-side constants (D col = l16 = (vvs, bs); D rows = o_b + r)
    const int vvs = l16 >> 2;
    const int bs  = l16 & 3;
    const int o_b = w * 16 + g4 * 4;
    const f32x4 bias4 = *(const f32x4*)(conv_b + o_b);
    float* const ob_base = out + (size_t)(bs * 64 + o_b) * VN;

    const char* ar = smem + l16 * LDA_B + g4 * 16;
    const __bf16* wfp = wf + ((size_t)(w * 18) * 64 + lane) * 8;

#define INTERP_WRITE(GV, VBASE)                                               \
    _Pragma("unroll")                                                         \
    for (int vv = 0; vv < 4; ++vv) {                                          \
        const int v  = (VBASE) + vv;                                          \
        const int vm = (v < VN) ? v : VN - 1;                                 \
        const float* am = itp_mat + (size_t)vm * 81;    /* scalar path */     \
        float s[9];                                                           \
        _Pragma("unroll")                                                     \
        for (int j = 0; j < 9; ++j) s[j] = 0.f;                               \
        _Pragma("unroll")                                                     \
        for (int k = 0; k < 9; ++k) {                                         \
            const float gk = GV[vv][k];                                       \
            _Pragma("unroll")                                                 \
            for (int j = 0; j < 9; ++j) s[j] += gk * am[k * 9 + j];           \
        }                                                                     \
        __bf16* rowp = (__bf16*)(smem + (vv * 4 + w) * LDA_B) + lane * 9;     \
        _Pragma("unroll")                                                     \
        for (int j = 0; j < 9; ++j) rowp[j] = (__bf16)s[j];                   \
    }

#define GATHER(GV, VBASE)                                                     \
    _Pragma("unroll")                                                         \
    for (int vv = 0; vv < 4; ++vv) {                                          \
        const int v  = (VBASE) + vv;                                          \
        const int vm = (v < VN) ? v : VN - 1;                                 \
        const int* idxv = index + (size_t)vm * 9;       /* s_load */          \
        _Pragma("unroll")                                                     \
        for (int k = 0; k < 9; ++k)                                           \
            GV[vv][k] = (float)xt[(size_t)idxv[k] * 256 + tid];               \
    }

#define MFMA_STORE(VBASE) {                                                   \
    f32x4 acc = {0.f, 0.f, 0.f, 0.f};                                         \
    _Pragma("unroll")                                                         \
    for (int ks = 0; ks < 18; ++ks) {                                         \
        bf16x8 a  = *(const bf16x8*)(ar + ks * 64);                           \
        bf16x8 wb = *(const bf16x8*)(wfp + (size_t)ks * 512);                 \
        acc = __builtin_amdgcn_mfma_f32_16x16x32_bf16(wb, a, acc, 0, 0, 0);   \
    }                                                                         \
    const int v_s = (VBASE) + vvs;                                            \
    if (v_s < VN) {                                                           \
        float* ob = ob_base + v_s;                                            \
        _Pragma("unroll")                                                     \
        for (int r = 0; r < 4; ++r)                                           \
            ob[(size_t)r * VN] = acc[r] + bias4[r];                           \
    } }

#define RAW_BARRIER() do {                                                    \
        asm volatile("s_waitcnt lgkmcnt(0)" ::: "memory");                    \
        __builtin_amdgcn_s_barrier();                                         \
    } while (0)

    // ---------------- sub0: gather -> interp -> ds_write ----------------
    float gv[4][9];
    GATHER(gv, v0)
    INTERP_WRITE(gv, v0)

    // ---------------- issue sub1 gathers (fly across barriers/MFMA) ------
    float gn[4][9];
    GATHER(gn, v0 + 4)

    RAW_BARRIER();             // (1) A-tile(sub0) ready; sub1 gathers in flight
    MFMA_STORE(v0)             // MFMA sub0 + direct store
    RAW_BARRIER();             // (2) all A-tile reads done -> writable

    // ---------------- sub1: interp (waits own vmcnt) -> ds_write ---------
    INTERP_WRITE(gn, v0 + 4)
    RAW_BARRIER();             // (3) A-tile(sub1) ready
    MFMA_STORE(v0 + 4)

#undef INTERP_WRITE
#undef GATHER
#undef MFMA_STORE
#undef RAW_BARRIER
}

// ---------------------------------------------------------------------------
extern "C" void kernel_launch(void* const* d_in, const int* in_sizes, int n_in,
                              void* d_out, int out_size, void* d_ws, size_t ws_size,
                              hipStream_t stream) {
    const float* x       = (const float*)d_in[0];
    const int*   index   = (const int*)d_in[1];
    const float* itp_mat = (const float*)d_in[2];
    const float* conv_w  = (const float*)d_in[3];
    const float* conv_b  = (const float*)d_in[4];
    float* out = (float*)d_out;

    __bf16* xt = (__bf16*)d_ws;                          // 20,972,544 B
    __bf16* wfrag = (__bf16*)((char*)d_ws + XT_BYTES);   // + 73,728 B

    dim3 tgrid((VN + 63) / 64, 4, 1);
    k_transpose<<<tgrid, 256, 0, stream>>>(x, xt);
    k_wprep<<<72, 64, 0, stream>>>(conv_w, wfrag);
    k_fused<<<NGB, 256, 0, stream>>>(xt, index, itp_mat, wfrag, conv_b, out);
}